// Round 1
// baseline (507.816 us; speedup 1.0000x reference)
//
#include <hip/hip_runtime.h>
#include <math.h>

typedef __bf16 bf16x8 __attribute__((ext_vector_type(8)));
typedef float f32x4 __attribute__((ext_vector_type(4)));
typedef unsigned int uint4v __attribute__((ext_vector_type(4)));

#define TWO_PI_F 6.28318530717958647692f
#define INV_4PI_F 0.079577471545947667884f

// packed-weight layout offsets in __bf16 elements inside d_ws
#define W1F_OFF 0
#define W1B_OFF 524288
#define W2F_OFF 1048576
#define W2B_OFF 1114112
#define W3F_OFF 1179648
#define W3B_OFF 1245184
#define W4F_OFF 1310720
#define W4B_OFF 1376256
#define PACK_CHUNKS_TOTAL 180224   // 65536*2 + 8192*6 chunks of 8 bf16

// ---------------------------------------------------------------------------
// Pack fp32 weights into bf16 MFMA B-operand tile order.
// Forward GEMM (H @ W): B[k][n] = W[k][n]. Backward (G @ W^T): B[k][n] = W[n][k].
// Layout (N=256 case): chunk c = ((kc*16+ct)*4+q)*16+n holds B[kc*32+q*8+j][ct*16+n], j=0..7
// W1-backward (N=2048): chunk c = ((ct*8+kc)*4+q)*16+n  (ct-major so one ct' block = 8KB contiguous)
// ---------------------------------------------------------------------------
__global__ void k_pack(const float* __restrict__ W1, const float* __restrict__ W2,
                       const float* __restrict__ W3, const float* __restrict__ W4,
                       __bf16* __restrict__ ws) {
  int gid = blockIdx.x * blockDim.x + threadIdx.x;
  if (gid >= PACK_CHUNKS_TOTAL) return;
  const float* W; int n, q, ct, kc; bool bwd; long dstoff;
  if (gid < 65536) {                       // W1 forward: K=2048, N=256
    int c = gid; n = c & 15; q = (c >> 4) & 3; ct = (c >> 6) & 15; kc = c >> 10;
    W = W1; bwd = false; dstoff = W1F_OFF + (long)c * 8;
  } else if (gid < 131072) {               // W1 backward: K=256, N=2048, ct-major
    int c = gid - 65536; n = c & 15; q = (c >> 4) & 3; kc = (c >> 6) & 7; ct = c >> 9;
    W = W1; bwd = true; dstoff = W1B_OFF + (long)c * 8;
  } else {                                 // W2..W4 fwd/bwd: K=N=256
    int g = gid - 131072; int r = g >> 13; int c = g & 8191;
    n = c & 15; q = (c >> 4) & 3; ct = (c >> 6) & 15; kc = c >> 10;
    W = (r < 2) ? W2 : (r < 4) ? W3 : W4; bwd = (r & 1);
    dstoff = W2F_OFF + (long)g * 8;
  }
  int k0 = kc * 32 + q * 8;
  int ngl = ct * 16 + n;
  bf16x8 v;
  #pragma unroll
  for (int j = 0; j < 8; ++j) {
    float f = bwd ? W[ngl * 256 + (k0 + j)] : W[(k0 + j) * 256 + ngl];
    v[j] = (__bf16)f;
  }
  *(bf16x8*)(ws + dstoff) = v;
}

// ---------------------------------------------------------------------------
// Biot-Savart: one thread per point, boundary loop staged in LDS. Writes alpha.
// out layout: f[N] | current[3N] | df[3N] | alpha[3N]
// ---------------------------------------------------------------------------
__global__ void k_biot(const float* __restrict__ x, const float* __restrict__ bdry,
                       float* __restrict__ out, int N, int M) {
  __shared__ float sb[512 * 3];
  int tid = threadIdx.x;
  for (int i = tid; i < M * 3; i += 256) sb[i] = bdry[i];
  __syncthreads();
  int idx = blockIdx.x * 256 + tid;
  if (idx >= N) return;
  float x0 = fminf(fmaxf(x[idx * 3 + 0], -1.f), 1.f);
  float x1 = fminf(fmaxf(x[idx * 3 + 1], -1.f), 1.f);
  float x2 = fminf(fmaxf(x[idx * 3 + 2], -1.f), 1.f);
  float a0 = 0.f, a1 = 0.f, a2 = 0.f;
  for (int s = 0; s < M; ++s) {
    int sn = (s + 1 == M) ? 0 : s + 1;
    float b0 = sb[s * 3 + 0], b1 = sb[s * 3 + 1], b2 = sb[s * 3 + 2];
    float c0 = sb[sn * 3 + 0], c1 = sb[sn * 3 + 1], c2 = sb[sn * 3 + 2];
    float e0 = c0 - b0, e1 = c1 - b1, e2 = c2 - b2;          // segment
    float m0 = 0.5f * (c0 + b0), m1 = 0.5f * (c1 + b1), m2 = 0.5f * (c2 + b2);
    float d0 = x0 - m0, d1 = x1 - m1, d2 = x2 - m2;
    float r2 = d0 * d0 + d1 * d1 + d2 * d2;
    float inv = rsqrtf(r2);
    float inv3 = inv * inv * inv;
    float n0 = e1 * d2 - e2 * d1;
    float n1 = e2 * d0 - e0 * d2;
    float n2 = e0 * d1 - e1 * d0;
    a0 = fmaf(n0, inv3, a0); a1 = fmaf(n1, inv3, a1); a2 = fmaf(n2, inv3, a2);
  }
  float* alpha = out + (size_t)7 * N;
  alpha[idx * 3 + 0] = a0 * INV_4PI_F;
  alpha[idx * 3 + 1] = a1 * INV_4PI_F;
  alpha[idx * 3 + 2] = a2 * INV_4PI_F;
}

// ---------------------------------------------------------------------------
// Fused MLP forward + input-gradient backward.
// Workgroup = 256 threads = 4 waves; wave owns 16 rows (M-tile). 64 rows/wg.
// ---------------------------------------------------------------------------
__launch_bounds__(256, 2)
__global__ void k_mlp(const float* __restrict__ x, const float* __restrict__ Brff,
                      const float* __restrict__ b1, const float* __restrict__ b2,
                      const float* __restrict__ b3, const float* __restrict__ b4,
                      const float* __restrict__ W5, const float* __restrict__ b5,
                      const __bf16* __restrict__ wsw, float* __restrict__ out, int N) {
  __shared__ __attribute__((aligned(16))) __bf16 sW[8192];      // 16KB weight-chunk stage
  __shared__ __attribute__((aligned(16))) __bf16 sConv[16384];  // 8KB/wave C->A conversion

  const int tid  = threadIdx.x;
  const int wave = tid >> 6;
  const int lane = tid & 63;
  const int ml   = lane & 15;   // A-row m / B-col n / C-col n
  const int quad = lane >> 4;
  const int rowbase = blockIdx.x * 64 + wave * 16;

  __bf16* conv = sConv + wave * 4096;

  // x for A-side rows (row = rowbase + ml)
  float xa0, xa1, xa2;
  {
    const float* xp = x + (size_t)(rowbase + ml) * 3;
    xa0 = fminf(fmaxf(xp[0], -1.f), 1.f);
    xa1 = fminf(fmaxf(xp[1], -1.f), 1.f);
    xa2 = fminf(fmaxf(xp[2], -1.f), 1.f);
  }
  // x for C-side rows (row = rowbase + quad*4 + r)
  float xr[4][3];
  #pragma unroll
  for (int r = 0; r < 4; ++r) {
    const float* xp = x + (size_t)(rowbase + quad * 4 + r) * 3;
    #pragma unroll
    for (int i = 0; i < 3; ++i) xr[r][i] = fminf(fmaxf(xp[i], -1.f), 1.f);
  }

  f32x4 acc[16];
  bf16x8 h1f[8], h2f[8], h3f[8], gf[8];

  auto stage16 = [&](const __bf16* src) {   // 16 KB: 256 threads x 4 x 16B
    const uint4v* s = (const uint4v*)src;
    uint4v* d = (uint4v*)sW;
    #pragma unroll
    for (int r = 0; r < 4; ++r) d[tid + r * 256] = s[tid + r * 256];
  };
  auto zero_acc = [&]() {
    #pragma unroll
    for (int ct = 0; ct < 16; ++ct) { f32x4 z = {0.f, 0.f, 0.f, 0.f}; acc[ct] = z; }
  };
  // C-layout (row=quad*4+r, col=ct*16+ml) -> conv index in A-frag tile order
  auto conv_widx = [&](int ct, int r) -> int {
    return (((ct >> 1) * 4 + ((ct & 1) << 1) + (ml >> 3)) * 16 + quad * 4 + r) * 8 + (ml & 7);
  };

  // ---- Forward layer 1: y(RFF) @ W1, K=2048 ----
  zero_acc();
  for (int kc = 0; kc < 64; ++kc) {
    int kbase = kc * 32 + quad * 8;
    int cb = kbase & 1023;
    const float* B0p = Brff + cb;
    const float* B1p = Brff + 1024 + cb;
    const float* B2p = Brff + 2048 + cb;
    bf16x8 af;
    #pragma unroll
    for (int j = 0; j < 8; ++j) {
      float t = xa0 * B0p[j] + xa1 * B1p[j] + xa2 * B2p[j];
      float v = (kc < 32) ? __sinf(TWO_PI_F * t) : __cosf(TWO_PI_F * t);
      af[j] = (__bf16)v;
    }
    __syncthreads();
    stage16(wsw + W1F_OFF + kc * 8192);
    __syncthreads();
    #pragma unroll
    for (int ct = 0; ct < 16; ++ct) {
      bf16x8 bfr = *(const bf16x8*)(sW + (ct * 4 + quad) * 128 + ml * 8);
      acc[ct] = __builtin_amdgcn_mfma_f32_16x16x32_bf16(af, bfr, acc[ct], 0, 0, 0);
    }
  }

  auto epilogue_h = [&](const float* __restrict__ bias, bf16x8* hf) {
    #pragma unroll
    for (int ct = 0; ct < 16; ++ct) {
      float bcol = bias[ct * 16 + ml];
      #pragma unroll
      for (int r = 0; r < 4; ++r) {
        float z = acc[ct][r] + bcol;
        float h = fmaxf(z, 0.f) + __logf(1.f + __expf(-fabsf(z)));  // softplus
        conv[conv_widx(ct, r)] = (__bf16)h;
      }
    }
    #pragma unroll
    for (int ks = 0; ks < 8; ++ks)
      hf[ks] = *(const bf16x8*)(conv + (ks * 4 + quad) * 128 + ml * 8);
  };

  auto gemm256 = [&](const bf16x8* af, const __bf16* wsrc) {  // K=256, N=256
    zero_acc();
    #pragma unroll
    for (int kc = 0; kc < 8; ++kc) {
      __syncthreads();
      stage16(wsrc + kc * 8192);
      __syncthreads();
      #pragma unroll
      for (int ct = 0; ct < 16; ++ct) {
        bf16x8 bfr = *(const bf16x8*)(sW + (ct * 4 + quad) * 128 + ml * 8);
        acc[ct] = __builtin_amdgcn_mfma_f32_16x16x32_bf16(af[kc], bfr, acc[ct], 0, 0, 0);
      }
    }
  };

  epilogue_h(b1, h1f);
  gemm256(h1f, wsw + W2F_OFF);
  epilogue_h(b2, h2f);
  gemm256(h2f, wsw + W3F_OFF);
  epilogue_h(b3, h3f);
  gemm256(h3f, wsw + W4F_OFF);

  // ---- Layer-4 epilogue: f head + g4 = sigma(z4)*W5 ----
  {
    float fpart[4] = {0.f, 0.f, 0.f, 0.f};
    #pragma unroll
    for (int ct = 0; ct < 16; ++ct) {
      float bcol = b4[ct * 16 + ml];
      float w5   = W5[ct * 16 + ml];
      #pragma unroll
      for (int r = 0; r < 4; ++r) {
        float z = acc[ct][r] + bcol;
        float ez = __expf(-fabsf(z));
        float sp = fmaxf(z, 0.f) + __logf(1.f + ez);
        float sig = (z >= 0.f) ? 1.f / (1.f + ez) : ez / (1.f + ez);
        fpart[r] += sp * w5;
        conv[conv_widx(ct, r)] = (__bf16)(sig * w5);
      }
    }
    #pragma unroll
    for (int r = 0; r < 4; ++r) {
      float v = fpart[r];
      #pragma unroll
      for (int m = 1; m < 16; m <<= 1) v += __shfl_xor(v, m, 64);
      if (ml == 0) out[rowbase + quad * 4 + r] = v + b5[0];
    }
    #pragma unroll
    for (int ks = 0; ks < 8; ++ks)
      gf[ks] = *(const bf16x8*)(conv + (ks * 4 + quad) * 128 + ml * 8);
  }

  // ---- Backward: g_{l-1} = (g_l @ W_l^T) * sigma(z_{l-1}); sigma = 1 - exp(-h) ----
  auto epilogue_g = [&](const bf16x8* hf) {
    #pragma unroll
    for (int ct = 0; ct < 16; ++ct) {
      #pragma unroll
      for (int r = 0; r < 4; ++r) conv[conv_widx(ct, r)] = (__bf16)acc[ct][r];
    }
    #pragma unroll
    for (int ks = 0; ks < 8; ++ks) {
      bf16x8 t = *(const bf16x8*)(conv + (ks * 4 + quad) * 128 + ml * 8);
      bf16x8 o;
      #pragma unroll
      for (int j = 0; j < 8; ++j) {
        float gp = (float)t[j];
        float h  = (float)hf[ks][j];
        o[j] = (__bf16)(gp * (1.f - __expf(-h)));
      }
      gf[ks] = o;
    }
  };

  gemm256(gf, wsw + W4B_OFF); epilogue_g(h3f);
  gemm256(gf, wsw + W3B_OFF); epilogue_g(h2f);
  gemm256(gf, wsw + W2B_OFF); epilogue_g(h1f);

  // ---- Backward L1: dy = g1 @ W1^T fused with dproj & dx; cols paired (c, c+1024) ----
  float dxa[4][3];
  #pragma unroll
  for (int r = 0; r < 4; ++r) { dxa[r][0] = 0.f; dxa[r][1] = 0.f; dxa[r][2] = 0.f; }

  for (int p = 0; p < 64; ++p) {
    __syncthreads();
    {
      const uint4v* base = (const uint4v*)(wsw + W1B_OFF);
      const uint4v* sA = base + (size_t)p * 512;
      const uint4v* sB = base + (size_t)(p + 64) * 512;
      uint4v* d = (uint4v*)sW;
      #pragma unroll
      for (int r = 0; r < 4; ++r) {
        int idx = tid + r * 256;
        d[idx] = (idx < 512) ? sA[idx] : sB[idx - 512];
      }
    }
    __syncthreads();
    f32x4 aA = {0.f, 0.f, 0.f, 0.f}, aB = {0.f, 0.f, 0.f, 0.f};
    #pragma unroll
    for (int ks = 0; ks < 8; ++ks) {
      bf16x8 bA = *(const bf16x8*)(sW + (ks * 4 + quad) * 128 + ml * 8);
      bf16x8 bB = *(const bf16x8*)(sW + 4096 + (ks * 4 + quad) * 128 + ml * 8);
      aA = __builtin_amdgcn_mfma_f32_16x16x32_bf16(gf[ks], bA, aA, 0, 0, 0);
      aB = __builtin_amdgcn_mfma_f32_16x16x32_bf16(gf[ks], bB, aB, 0, 0, 0);
    }
    int c = p * 16 + ml;
    float B0 = Brff[c], B1 = Brff[1024 + c], B2 = Brff[2048 + c];
    #pragma unroll
    for (int r = 0; r < 4; ++r) {
      float t = xr[r][0] * B0 + xr[r][1] * B1 + xr[r][2] * B2;
      float sn, cs;
      __sincosf(TWO_PI_F * t, &sn, &cs);
      float dp = aA[r] * cs - aB[r] * sn;
      dxa[r][0] = fmaf(dp, B0, dxa[r][0]);
      dxa[r][1] = fmaf(dp, B1, dxa[r][1]);
      dxa[r][2] = fmaf(dp, B2, dxa[r][2]);
    }
  }

  #pragma unroll
  for (int r = 0; r < 4; ++r) {
    #pragma unroll
    for (int i = 0; i < 3; ++i) {
      float v = dxa[r][i] * TWO_PI_F;
      #pragma unroll
      for (int m = 1; m < 16; m <<= 1) v += __shfl_xor(v, m, 64);
      if (ml == 0) {
        int row = rowbase + quad * 4 + r;
        out[(size_t)4 * N + row * 3 + i] = v;                                   // df
        out[(size_t)N + row * 3 + i] = v + out[(size_t)7 * N + row * 3 + i];    // current
      }
    }
  }
}

extern "C" void kernel_launch(void* const* d_in, const int* in_sizes, int n_in,
                              void* d_out, int out_size, void* d_ws, size_t ws_size,
                              hipStream_t stream) {
  const float* x    = (const float*)d_in[0];
  const float* bdry = (const float*)d_in[1];
  const float* Brff = (const float*)d_in[2];
  const float* W1   = (const float*)d_in[3];
  const float* b1   = (const float*)d_in[4];
  const float* W2   = (const float*)d_in[5];
  const float* b2   = (const float*)d_in[6];
  const float* W3   = (const float*)d_in[7];
  const float* b3   = (const float*)d_in[8];
  const float* W4   = (const float*)d_in[9];
  const float* b4   = (const float*)d_in[10];
  const float* W5   = (const float*)d_in[11];
  const float* b5   = (const float*)d_in[12];
  float* out = (float*)d_out;
  __bf16* ws = (__bf16*)d_ws;
  int N = in_sizes[0] / 3;   // 65536
  int M = in_sizes[1] / 3;   // 512

  k_pack<<<(PACK_CHUNKS_TOTAL + 255) / 256, 256, 0, stream>>>(W1, W2, W3, W4, ws);
  k_biot<<<(N + 255) / 256, 256, 0, stream>>>(x, bdry, out, N, M);
  k_mlp<<<N / 64, 256, 0, stream>>>(x, Brff, b1, b2, b3, b4, W5, b5, ws, out, N);
}